// Round 7
// baseline (46483.951 us; speedup 1.0000x reference)
//
#include <hip/hip_runtime.h>

// 2-layer LSTM, B=64, S=2048, F=40, EMB=128, HID=256 — R7 "parity-tagged,
// barrier-free, LDS-free" design.
// 32 blocks = 4 groups x {L0,L1} x 4 slices (64 cols), 512 thr. All waves are
// autonomous: A-fragments are loaded DIRECTLY from the h-rings into registers
// in MFMA layout (imm-offset u64 atomic loads), freshness certified per-word
// by a ring-parity bit stolen from the LSB of each bf16-lo half (1-RT, full
// payload density). No __syncthreads, no LDS, no sentinels, no fences.
// Ring depth 16; parity = ~((t>>4)&1) so 0xAA poison (parity bits 0) can never
// alias the first wrap. L0 overwrite of h0(t-16) gated by a signed L1-progress
// probe (0xAA poison reads negative => safe without init).
// Numerics: weights bf16 (R6-verbatim fragments), A hi/lo bf16 split, c/h/gates
// fp32, gate-combine via shfl_xor (R5/R6-verified mapping).

#define Sz 2048

typedef __attribute__((ext_vector_type(8))) short short8;
typedef __attribute__((ext_vector_type(4))) float f32x4;

// ws u64 offsets: ring = [g][slot16][m16][cp128]
#define RING0 0
#define RING1 131072
#define PROBE 262144          // probe[g] at PROBE + g*16

__device__ __forceinline__ unsigned short bf16_rne(float f) {
  unsigned u = __float_as_uint(f);
  u += 0x7FFFu + ((u >> 16) & 1u);
  return (unsigned short)(u >> 16);
}
__device__ __forceinline__ unsigned pk_enc(float f) {
  unsigned short hb = bf16_rne(f);
  float fh = __uint_as_float((unsigned)hb << 16);
  unsigned short lb = bf16_rne(f - fh);
  return ((unsigned)hb << 16) | (unsigned)lb;
}
__device__ __forceinline__ void x_frag(const float* xf, short8& aH, short8& aL) {
  union { short8 v; unsigned short u[8]; } h, l;
#pragma unroll
  for (int z = 0; z < 8; ++z) {
    unsigned short hb = bf16_rne(xf[z]);
    h.u[z] = hb;
    l.u[z] = bf16_rne(xf[z] - __uint_as_float((unsigned)hb << 16));
  }
  aH = h.v; aL = l.v;
}

// 16 words = 4 k-tiles of A-fragments for this lane (imm-offset loads)
__device__ __forceinline__ void load16(const unsigned long long* __restrict__ p,
                                       unsigned long long* v) {
#pragma unroll
  for (int k = 0; k < 16; ++k)
    v[k] = __hip_atomic_load(p + (k >> 2) * 16 + (k & 3), __ATOMIC_RELAXED,
                             __HIP_MEMORY_SCOPE_AGENT);
}
__device__ __forceinline__ void spin16(const unsigned long long* __restrict__ p,
                                       unsigned long long* v, unsigned par3) {
  unsigned pend = 0;
#pragma unroll
  for (int k = 0; k < 16; ++k)
    if (((unsigned)(v[k] >> 32) & 0x00010001u) != par3) pend |= 1u << k;
  int fails = 0;
  while (__any((int)pend)) {
    if (++fails > 3) __builtin_amdgcn_s_sleep(1);
#pragma unroll
    for (int k = 0; k < 16; ++k)
      if (pend & (1u << k)) {
        unsigned long long x = __hip_atomic_load(p + (k >> 2) * 16 + (k & 3),
                                                 __ATOMIC_RELAXED,
                                                 __HIP_MEMORY_SCOPE_AGENT);
        v[k] = x;
        if (((unsigned)(x >> 32) & 0x00010001u) == par3) pend &= ~(1u << k);
      }
  }
}
// consume 16 words: 4 k-tiles x {hi,lo} x 2 accumulators
__device__ __forceinline__ void mfma16(const unsigned long long* v,
                                       const short8* w0, const short8* w1,
                                       f32x4* acc) {
#pragma unroll
  for (int kk = 0; kk < 4; ++kk) {
    union { short8 s; unsigned d[4]; } aH, aL;
#pragma unroll
    for (int i = 0; i < 4; ++i) {
      aH.d[i] = (unsigned)v[kk * 4 + i];
      aL.d[i] = (unsigned)(v[kk * 4 + i] >> 32);
    }
    acc[0] = __builtin_amdgcn_mfma_f32_16x16x32_bf16(aH.s, w0[kk], acc[0], 0, 0, 0);
    acc[0] = __builtin_amdgcn_mfma_f32_16x16x32_bf16(aL.s, w0[kk], acc[0], 0, 0, 0);
    acc[1] = __builtin_amdgcn_mfma_f32_16x16x32_bf16(aH.s, w1[kk], acc[1], 0, 0, 0);
    acc[1] = __builtin_amdgcn_mfma_f32_16x16x32_bf16(aL.s, w1[kk], acc[1], 0, 0, 0);
  }
}

__global__ void init_out(const float* __restrict__ b_out, float* __restrict__ out) {
  int i = blockIdx.x * 512 + threadIdx.x;
  if (i < 64 * Sz) out[i] = b_out[0];
}

__global__ __launch_bounds__(512, 2) void lstm_v7(
    const float* __restrict__ xin, const float* __restrict__ W_in,
    const float* __restrict__ b_in, const float* __restrict__ W_ih0,
    const float* __restrict__ W_hh0, const float* __restrict__ b_ih0,
    const float* __restrict__ b_hh0, const float* __restrict__ W_ih1,
    const float* __restrict__ W_hh1, const float* __restrict__ b_ih1,
    const float* __restrict__ b_hh1, const float* __restrict__ W_out,
    const float* __restrict__ b_out, float* __restrict__ out,
    unsigned long long* __restrict__ ws64) {
  const int bx = blockIdx.x;
  if (bx >= 32) return;
  const int g = bx & 3;
  const int L = (bx >> 2) & 1;
  const int s = bx >> 3;          // slice 0..3 (64 cols)
  const int tid = (int)threadIdx.x;
  const int w = tid >> 6;         // wave 0..7 (8 cols each)
  const int lane = tid & 63;
  const int q = lane >> 4, n16 = lane & 15;
  const int gidx = n16 >> 2, c4 = n16 & 3;

  // ---------------- persistent weights (R6-verbatim) ----------------
  short8 wfA[2][8];   // L0: W_hh0 ; L1: W_ih1   (x h0 fragments)
  short8 wfB[2][8];   // L0: W_comb (kt<2) ; L1: W_hh1 (x h1 fragments)
  float bb[2];
  float wo2[2] = {0.f, 0.f};
  {
    const float* WA = L ? W_ih1 : W_hh0;
#pragma unroll
    for (int j = 0; j < 2; ++j) {
      const int col = s * 64 + w * 8 + c4 * 2 + j;
      const int row = gidx * 256 + col;
#pragma unroll
      for (int kt = 0; kt < 8; ++kt) {
        const float* src = WA + (size_t)row * 256 + kt * 32 + q * 8;
        union { short8 v; unsigned short u[8]; } fr;
#pragma unroll
        for (int z = 0; z < 8; ++z) fr.u[z] = bf16_rne(src[z]);
        wfA[j][kt] = fr.v;
      }
      if (L) {
#pragma unroll
        for (int kt = 0; kt < 8; ++kt) {
          const float* src = W_hh1 + (size_t)row * 256 + kt * 32 + q * 8;
          union { short8 v; unsigned short u[8]; } fr;
#pragma unroll
          for (int z = 0; z < 8; ++z) fr.u[z] = bf16_rne(src[z]);
          wfB[j][kt] = fr.v;
        }
        bb[j] = b_ih1[row] + b_hh1[row];
        wo2[j] = W_out[col];
      } else {
        float sv0[8], sv1[8];
#pragma unroll
        for (int z = 0; z < 8; ++z) { sv0[z] = 0.f; sv1[z] = 0.f; }
        float bacc = 0.f;
        const float* wr = W_ih0 + (size_t)row * 128;
        for (int e = 0; e < 128; ++e) {
          float wv = wr[e];
          const float* wiv = W_in + e * 40;
          bacc += wv * b_in[e];
#pragma unroll
          for (int z = 0; z < 8; ++z) sv0[z] += wv * wiv[q * 8 + z];
          if (q == 0) {
#pragma unroll
            for (int z = 0; z < 8; ++z) sv1[z] += wv * wiv[32 + z];
          }
        }
        union { short8 v; unsigned short u[8]; } f0, f1;
#pragma unroll
        for (int z = 0; z < 8; ++z) {
          f0.u[z] = bf16_rne(sv0[z]);
          f1.u[z] = (q == 0) ? bf16_rne(sv1[z]) : (unsigned short)0;
        }
        wfB[j][0] = f0.v; wfB[j][1] = f1.v;
        bb[j] = b_ih0[row] + b_hh0[row] + bacc;
      }
    }
  }

  float cst[2][4] = {{0.f, 0.f, 0.f, 0.f}, {0.f, 0.f, 0.f, 0.f}};
  const bool g0b = gidx & 1, g1b = gidx & 2;
  const float sc = (gidx == 2) ? 2.f : 1.f;
  // publish coords: m = q*4+gidx, colpair cp = s*32 + w*4 + c4
  const int pub_off = (q * 4 + gidx) * 128 + (s * 32 + w * 4 + c4);
  // fragment-read base offset within a slot: [m=n16][cp = kt*16 + q*4 + i]
  const int frag_off = n16 * 128 + q * 4;
  unsigned long long* const ringMy = ws64 + (L ? RING1 : RING0) + (size_t)g * 2048 * 16 / 16 * 16; // g*32768? computed below
  (void)ringMy;

#pragma unroll 1
  for (int t = 0; t < Sz; ++t) {
    const unsigned parW3 = (((((unsigned)t >> 4) & 1u) ^ 1u)) ? 0x00010001u : 0u;
    f32x4 acc[2] = {{0.f, 0.f, 0.f, 0.f}, {0.f, 0.f, 0.f, 0.f}};

    if (L == 0) {
      // x(t) loads + fragments (overlap with h0 loads in flight)
      const float* xp = xin + ((size_t)(g * 16 + n16) * Sz + t) * 40;
      float4 xa = *(const float4*)(xp + q * 8);
      float4 xb4 = *(const float4*)(xp + q * 8 + 4);
      float4 xc, xd;
      if (q == 0) { xc = *(const float4*)(xp + 32); xd = *(const float4*)(xp + 36); }

      unsigned long long v0[16], v1[16];
      const unsigned long long* p0 = nullptr;
      unsigned par3 = 0;
      if (t > 0) {
        const int slot = (t - 1) & 15;
        par3 = (((((unsigned)(t - 1) >> 4) & 1u) ^ 1u)) ? 0x00010001u : 0u;
        p0 = ws64 + RING0 + ((size_t)(g * 16 + slot) * 16) * 128 + frag_off;
        load16(p0, v0);
        load16(p0 + 64, v1);
      }
      {  // x MFMAs while h0 loads fly
        short8 axH, axL;
        float xf[8] = {xa.x, xa.y, xa.z, xa.w, xb4.x, xb4.y, xb4.z, xb4.w};
        x_frag(xf, axH, axL);
        acc[0] = __builtin_amdgcn_mfma_f32_16x16x32_bf16(axH, wfB[0][0], acc[0], 0, 0, 0);
        acc[0] = __builtin_amdgcn_mfma_f32_16x16x32_bf16(axL, wfB[0][0], acc[0], 0, 0, 0);
        acc[1] = __builtin_amdgcn_mfma_f32_16x16x32_bf16(axH, wfB[1][0], acc[1], 0, 0, 0);
        acc[1] = __builtin_amdgcn_mfma_f32_16x16x32_bf16(axL, wfB[1][0], acc[1], 0, 0, 0);
        float xg[8] = {0, 0, 0, 0, 0, 0, 0, 0};
        if (q == 0) {
          xg[0] = xc.x; xg[1] = xc.y; xg[2] = xc.z; xg[3] = xc.w;
          xg[4] = xd.x; xg[5] = xd.y; xg[6] = xd.z; xg[7] = xd.w;
        }
        x_frag(xg, axH, axL);
        acc[0] = __builtin_amdgcn_mfma_f32_16x16x32_bf16(axH, wfB[0][1], acc[0], 0, 0, 0);
        acc[0] = __builtin_amdgcn_mfma_f32_16x16x32_bf16(axL, wfB[0][1], acc[0], 0, 0, 0);
        acc[1] = __builtin_amdgcn_mfma_f32_16x16x32_bf16(axH, wfB[1][1], acc[1], 0, 0, 0);
        acc[1] = __builtin_amdgcn_mfma_f32_16x16x32_bf16(axL, wfB[1][1], acc[1], 0, 0, 0);
      }
      if (t > 0) {
        spin16(p0, v0, par3);
        mfma16(v0, &wfA[0][0], &wfA[1][0], acc);
        spin16(p0 + 64, v1, par3);
        mfma16(v1, &wfA[0][4], &wfA[1][4], acc);
      }
      // throttle before overwriting h0(t-16): needs L1 progress >= t-14
      if (t >= 16) {
        const unsigned long long* pp = ws64 + PROBE + g * 16;
        int f = 0;
        for (;;) {
          long long pv = (long long)__hip_atomic_load(pp, __ATOMIC_RELAXED,
                                                      __HIP_MEMORY_SCOPE_AGENT);
          if (pv >= (long long)(t - 14)) break;
          if (++f > 2) __builtin_amdgcn_s_sleep(1);
        }
      }
    } else {
      // ---- L1: h0(t) fragments, then h1(t-1) ----
      unsigned long long v0[16], v1[16];
      const int slot0 = t & 15;
      const unsigned long long* p0 =
          ws64 + RING0 + ((size_t)(g * 16 + slot0) * 16) * 128 + frag_off;
      load16(p0, v0);
      load16(p0 + 64, v1);
      spin16(p0, v0, parW3);
      mfma16(v0, &wfA[0][0], &wfA[1][0], acc);
      spin16(p0 + 64, v1, parW3);
      mfma16(v1, &wfA[0][4], &wfA[1][4], acc);
      if (t > 0) {
        const int slot1 = (t - 1) & 15;
        const unsigned par31 = (((((unsigned)(t - 1) >> 4) & 1u) ^ 1u)) ? 0x00010001u : 0u;
        const unsigned long long* p1 =
            ws64 + RING1 + ((size_t)(g * 16 + slot1) * 16) * 128 + frag_off;
        load16(p1, v0);
        load16(p1 + 64, v1);
        spin16(p1, v0, par31);
        mfma16(v0, &wfB[0][0], &wfB[1][0], acc);
        spin16(p1 + 64, v1, par31);
        mfma16(v1, &wfB[0][4], &wfB[1][4], acc);
      }
    }

    // ---- epilogue: gate-combine in-register (R5/R6-verified mapping) ----
    float hvv[2][4];
#pragma unroll
    for (int j = 0; j < 2; ++j) {
#pragma unroll
      for (int r = 0; r < 4; ++r) {
        float a = acc[j][r] + bb[j];
        float y = 1.f / (1.f + __expf(-a * sc));
        float v = fmaf(y, sc, 1.f - sc);
        float t1 = __shfl_xor(v, 4, 64);
        float t2 = __shfl_xor(v, 8, 64);
        float t3 = __shfl_xor(t1, 8, 64);
        float pi = g1b ? (g0b ? t3 : t2) : (g0b ? t1 : v);
        float pf = g1b ? (g0b ? t2 : t3) : (g0b ? v : t1);
        float pg = g1b ? (g0b ? t1 : v) : (g0b ? t3 : t2);
        float po = g1b ? (g0b ? v : t1) : (g0b ? t2 : t3);
        float c = pf * cst[j][r] + pi * pg;
        cst[j][r] = c;
        float th = 2.f / (1.f + __expf(-2.f * c)) - 1.f;
        hvv[j][r] = po * th;
      }
    }
    // publish cols (c0, c0+1) for m = q*4+gidx as one parity-tagged u64
    float h0s = hvv[0][0], h1s = hvv[1][0];
    if (gidx == 1) { h0s = hvv[0][1]; h1s = hvv[1][1]; }
    else if (gidx == 2) { h0s = hvv[0][2]; h1s = hvv[1][2]; }
    else if (gidx == 3) { h0s = hvv[0][3]; h1s = hvv[1][3]; }
    const unsigned pk0 = pk_enc(h0s), pk1 = pk_enc(h1s);
    const unsigned loD = (pk0 >> 16) | (pk1 & 0xFFFF0000u);              // hi-halves
    const unsigned hiD = (((pk0 & 0xFFFFu) | (pk1 << 16)) & 0xFFFEFFFEu) | parW3;
    const unsigned long long val = ((unsigned long long)hiD << 32) | loD;
    __hip_atomic_store(ws64 + (L ? RING1 : RING0) +
                           ((size_t)(g * 16 + (t & 15)) * 16) * 128 + pub_off,
                       val, __ATOMIC_RELAXED, __HIP_MEMORY_SCOPE_AGENT);

    if (L == 1) {
      // out-projection: sum over this wave's 8 cols, all 4 batches
      float vr[4];
#pragma unroll
      for (int r = 0; r < 4; ++r) {
        float v = hvv[0][r] * wo2[0] + hvv[1][r] * wo2[1];
        v += __shfl_xor(v, 1, 64);
        v += __shfl_xor(v, 2, 64);
        vr[r] = v;
      }
      if (n16 == 0) {
#pragma unroll
        for (int r = 0; r < 4; ++r)
          atomicAdd(out + (size_t)(g * 16 + q * 4 + r) * Sz + t, vr[r]);
      }
      // progress probe (one wave per group)
      if (s == 0 && w == 0 && lane == 0)
        __hip_atomic_store(ws64 + PROBE + g * 16, (unsigned long long)(t + 1),
                           __ATOMIC_RELAXED, __HIP_MEMORY_SCOPE_AGENT);
    }
  }
}

extern "C" void kernel_launch(void* const* d_in, const int* in_sizes, int n_in,
                              void* d_out, int out_size, void* d_ws, size_t ws_size,
                              hipStream_t stream) {
  const float* xin   = (const float*)d_in[0];
  const float* W_in  = (const float*)d_in[1];
  const float* b_in  = (const float*)d_in[2];
  const float* W_ih0 = (const float*)d_in[3];
  const float* W_hh0 = (const float*)d_in[4];
  const float* b_ih0 = (const float*)d_in[5];
  const float* b_hh0 = (const float*)d_in[6];
  const float* W_ih1 = (const float*)d_in[7];
  const float* W_hh1 = (const float*)d_in[8];
  const float* b_ih1 = (const float*)d_in[9];
  const float* b_hh1 = (const float*)d_in[10];
  const float* W_out = (const float*)d_in[11];
  const float* b_out = (const float*)d_in[12];
  float* out = (float*)d_out;
  unsigned long long* ws64 = (unsigned long long*)d_ws;

  init_out<<<(64 * Sz + 511) / 512, 512, 0, stream>>>(b_out, out);
  lstm_v7<<<32, 512, 0, stream>>>(xin, W_in, b_in, W_ih0, W_hh0, b_ih0, b_hh0,
                                  W_ih1, W_hh1, b_ih1, b_hh1, W_out, b_out,
                                  out, ws64);
}